// Round 4
// baseline (559.702 us; speedup 1.0000x reference)
//
#include <hip/hip_runtime.h>
#include <stdint.h>

typedef unsigned short u16;
typedef __attribute__((ext_vector_type(8))) short bf16x8v;   // 8 bf16 = 4 VGPR (MFMA A/B frag)
typedef __attribute__((ext_vector_type(4))) float f32x4;     // MFMA C/D frag

#define DIM   2048
#define NH    16
#define NKV   8
#define HD    64
#define B_    2
#define S_    2048
#define ROWS  (B_*S_)     // 4096
#define NQKV  4096
#define EPS_   1e-5f
#define SCALE_ 0.125f     // 64^-0.5
#define RESCALE_THR 8.0f  // T13 defer-max threshold (HK value)

__device__ __forceinline__ u16 bfbits(float f) {
  union { float f; unsigned int u; } a; a.f = f;
  unsigned int u = a.u;
  return (u16)((u + 0x7FFFu + ((u >> 16) & 1u)) >> 16);   // RNE f32->bf16
}

__device__ __forceinline__ f32x4 mfma16(bf16x8v a, bf16x8v b, f32x4 c) {
  return __builtin_amdgcn_mfma_f32_16x16x32_bf16(a, b, c, 0, 0, 0);
}

__device__ __forceinline__ void gload_lds16(const void* g, void* l) {
  __builtin_amdgcn_global_load_lds(
      (const __attribute__((address_space(1))) unsigned int*)g,
      (__attribute__((address_space(3))) unsigned int*)l, 16, 0, 0);
}

// ---------------- elementwise cast x -> bf16 ----------------
__global__ void cast_f32_bf16(const float* __restrict__ src, u16* __restrict__ dst, int n4) {
  int i = blockIdx.x * 256 + threadIdx.x;
  if (i >= n4) return;
  float4 v = ((const float4*)src)[i];
  ushort4 o; o.x = bfbits(v.x); o.y = bfbits(v.y); o.z = bfbits(v.z); o.w = bfbits(v.w);
  ((ushort4*)dst)[i] = o;
}

// ---------------- transpose-cast: src fp32 [R][C] -> dst bf16 [C][R] ----------------
__global__ void transpose_cast(const float* __restrict__ src, u16* __restrict__ dst, int R, int C) {
  __shared__ float t[32][33];
  int c0 = blockIdx.x * 32, r0 = blockIdx.y * 32;
  int x = threadIdx.x, y = threadIdx.y;
#pragma unroll
  for (int i = 0; i < 4; ++i) t[y + 8*i][x] = src[(size_t)(r0 + y + 8*i) * C + c0 + x];
  __syncthreads();
#pragma unroll
  for (int i = 0; i < 4; ++i) dst[(size_t)(c0 + y + 8*i) * R + r0 + x] = bfbits(t[x][y + 8*i]);
}

// ---------------- V transpose: qkv fp32 [row][3072 + kv*128 + dv] -> Vt bf16 [b][kv][dv][s] ----------------
__global__ void v_transpose(const float* __restrict__ qkv, u16* __restrict__ Vt) {
  __shared__ float t[32][33];
  int z = blockIdx.z;                // b*8+kv
  int b = z >> 3, kv = z & 7;
  int s0 = blockIdx.x * 32, d0 = blockIdx.y * 32;
  int x = threadIdx.x, y = threadIdx.y;
  const float* src = qkv + (size_t)b * S_ * NQKV + 3072 + kv * 128;
#pragma unroll
  for (int i = 0; i < 4; ++i) t[y + 8*i][x] = src[(size_t)(s0 + y + 8*i) * NQKV + d0 + x];
  __syncthreads();
  u16* dst = Vt + ((size_t)(b * NKV + kv) * 128) * S_;
#pragma unroll
  for (int i = 0; i < 4; ++i) dst[(size_t)(d0 + y + 8*i) * S_ + s0 + x] = bfbits(t[x][y + 8*i]);
}

// ---------------- RoPE (interleaved) + split comps, fp32 in / bf16 out ----------------
// q: hshift=5 (32 rope-heads), coloff=0, D1/D2 have 16 heads.  k: hshift=4, coloff=2048, 8 heads.
__global__ void rope_kernel(const float* __restrict__ qkv, const float* __restrict__ fc,
                            const float* __restrict__ fs, u16* __restrict__ D1, u16* __restrict__ D2,
                            int hshift, int coloff) {
  int p = blockIdx.x * 256 + threadIdx.x;
  int i = p & 31;
  int hh = (p >> 5) & ((1 << hshift) - 1);
  int row = p >> (5 + hshift);
  int s = row & (S_ - 1);
  int b = row >> 11;
  const float* src = qkv + (size_t)row * NQKV + coloff + hh * HD + 2 * i;
  float e = src[0], o = src[1];
  float c = fc[s * 32 + i], sn = fs[s * 32 + i];
  float r0 = e * c - o * sn, r1 = e * sn + o * c;
  u16* dst = (hh & 1) ? D2 : D1;
  int nh = 1 << (hshift - 1);
  size_t offo = (((size_t)b * nh + (hh >> 1)) * S_ + s) * HD + 2 * i;
  unsigned int packed = (unsigned int)bfbits(r0) | ((unsigned int)bfbits(r1) << 16);
  *(unsigned int*)(dst + offo) = packed;
}

// ---------------- lambda scalars ----------------
__global__ void lambda_kernel(const float* lq1, const float* lk1, const float* lq2,
                              const float* lk2, const float* li, float* scal) {
  int t = threadIdx.x;   // 64
  float p1 = lq1[t] * lk1[t];
  float p2 = lq2[t] * lk2[t];
#pragma unroll
  for (int off = 32; off > 0; off >>= 1) { p1 += __shfl_xor(p1, off); p2 += __shfl_xor(p2, off); }
  if (t == 0) {
    scal[0] = __expf(p1) - __expf(p2) + li[0];  // lambda_full
    scal[1] = 1.0f - li[0];                     // output scale
  }
}

// ---------------- GEMM: C fp32 [M][N] = A bf16 [M][K] @ Bt bf16 [N][K]^T ----------------
__global__ __launch_bounds__(256) void gemm_bt(const u16* __restrict__ A, const u16* __restrict__ Bt,
                                               float* __restrict__ C, int M, int N, int K) {
  __shared__ u16 As[128 * 32];
  __shared__ u16 Bs[128 * 32];
  const int tid = threadIdx.x;
  const int wave = tid >> 6, lane = tid & 63;
  const int lr = lane & 15, lk = (lane >> 4) * 8;
  const size_t row0 = (size_t)blockIdx.y * 128, col0 = (size_t)blockIdx.x * 128;
  const int wr = (wave >> 1) * 64, wc = (wave & 1) * 64;
  f32x4 acc[4][4] = {};
  for (int kt = 0; kt < K; kt += 32) {
#pragma unroll
    for (int i = 0; i < 2; ++i) {
      int c = i * 256 + tid;
      int r = c >> 2, c8 = (c & 3) * 8;
      gload_lds16(A  + (row0 + r) * (size_t)K + kt + c8, (char*)As + (i * 256 + wave * 64) * 16);
      gload_lds16(Bt + (col0 + r) * (size_t)K + kt + c8, (char*)Bs + (i * 256 + wave * 64) * 16);
    }
    __syncthreads();
    bf16x8v af[4], bv[4];
#pragma unroll
    for (int m = 0; m < 4; ++m) af[m] = *(const bf16x8v*)(As + (wr + m * 16 + lr) * 32 + lk);
#pragma unroll
    for (int n = 0; n < 4; ++n) bv[n] = *(const bf16x8v*)(Bs + (wc + n * 16 + lr) * 32 + lk);
#pragma unroll
    for (int m = 0; m < 4; ++m)
#pragma unroll
      for (int n = 0; n < 4; ++n) acc[m][n] = mfma16(af[m], bv[n], acc[m][n]);
    __syncthreads();
  }
  const int crow = (lane >> 4) * 4;
#pragma unroll
  for (int m = 0; m < 4; ++m)
#pragma unroll
    for (int n = 0; n < 4; ++n) {
      float* cp = C + (row0 + wr + m * 16 + crow) * (size_t)N + col0 + wc + n * 16 + lr;
#pragma unroll
      for (int j = 0; j < 4; ++j) cp[(size_t)j * N] = acc[m][n][j];
    }
}

// ---------------- fused differential attention ----------------
// All LDS tiles are [rows][8 chunks of 16B] with XOR swizzle: physical chunk
// c_phys at row r holds logical chunk c_phys ^ (r&7). Staged via per-lane
// pre-swizzled global source (rule #21); every ds_read applies c ^ (r&7).
__device__ __forceinline__ void attn_step(const u16* Ks, const u16* Vts, u16* Pw,
                                          const bf16x8v* qf, float* m, float* l, f32x4* O,
                                          int lane) {
  const int lr = lane & 15, cq = lane >> 4, crow = cq * 4;
  f32x4 s[4] = {};
  __builtin_amdgcn_s_setprio(1);
#pragma unroll
  for (int kf = 0; kf < 4; ++kf) {
    const int row = kf * 16 + lr, sw = row & 7;
    s[kf] = mfma16(qf[0], *(const bf16x8v*)(Ks + row * 64 + ((cq ^ sw) * 8)), s[kf]);
    s[kf] = mfma16(qf[1], *(const bf16x8v*)(Ks + row * 64 + (((cq + 4) ^ sw) * 8)), s[kf]);
  }
  __builtin_amdgcn_s_setprio(0);
  float pm[4] = {-1e30f, -1e30f, -1e30f, -1e30f};
#pragma unroll
  for (int kf = 0; kf < 4; ++kf)
#pragma unroll
    for (int j = 0; j < 4; ++j) {
      float sv = s[kf][j] * SCALE_;
      s[kf][j] = sv;
      pm[j] = fmaxf(pm[j], sv);
    }
#pragma unroll
  for (int off = 1; off < 16; off <<= 1)
#pragma unroll
    for (int j = 0; j < 4; ++j) pm[j] = fmaxf(pm[j], __shfl_xor(pm[j], off));
  // T13 defer-max: skip O-rescale while tile max stays within THR of running max
  bool okl = true;
#pragma unroll
  for (int j = 0; j < 4; ++j) okl = okl && (pm[j] <= m[j] + RESCALE_THR);
  const bool defer = (__all(okl ? 1 : 0) != 0);
  float al[4], ps[4];
#pragma unroll
  for (int j = 0; j < 4; ++j) {
    if (defer) { al[j] = 1.f; }
    else {
      float mn = fmaxf(m[j], pm[j]);
      al[j] = __expf(m[j] - mn);
      m[j] = mn;
    }
    ps[j] = 0.f;
  }
#pragma unroll
  for (int kf = 0; kf < 4; ++kf)
#pragma unroll
    for (int j = 0; j < 4; ++j) {
      float p = __expf(s[kf][j] - m[j]);
      s[kf][j] = p;
      ps[j] += p;
    }
#pragma unroll
  for (int off = 1; off < 16; off <<= 1)
#pragma unroll
    for (int j = 0; j < 4; ++j) ps[j] += __shfl_xor(ps[j], off);
#pragma unroll
  for (int j = 0; j < 4; ++j) l[j] = l[j] * al[j] + ps[j];
  if (!defer) {
#pragma unroll
    for (int f = 0; f < 8; ++f)
#pragma unroll
      for (int j = 0; j < 4; ++j) O[f][j] *= al[j];
  }
  // P (C-layout) -> LDS (swizzled) so it can be re-read in A-layout
#pragma unroll
  for (int kf = 0; kf < 4; ++kf) {
    const int ch = kf * 2 + (lr >> 3), cl = lr & 7;   // col = kf*16+lr -> chunk, within-chunk
#pragma unroll
    for (int j = 0; j < 4; ++j) {
      const int row = crow + j;
      Pw[row * 64 + ((ch ^ (row & 7)) * 8) + cl] = bfbits(s[kf][j]);
    }
  }
  __builtin_amdgcn_s_setprio(1);
#pragma unroll
  for (int kst = 0; kst < 2; ++kst) {
    bf16x8v pf = *(const bf16x8v*)(Pw + lr * 64 + (((kst * 4 + cq) ^ (lr & 7)) * 8));
#pragma unroll
    for (int f = 0; f < 8; ++f) {
      const int row = f * 16 + lr;
      bf16x8v vf = *(const bf16x8v*)(Vts + row * 64 + (((kst * 4 + cq) ^ (row & 7)) * 8));
      O[f] = mfma16(pf, vf, O[f]);
    }
  }
  __builtin_amdgcn_s_setprio(0);
}

__device__ __forceinline__ void stage_tile(const u16* k1b, const u16* k2b, const u16* vb,
                                           int key0, u16* K1d, u16* K2d, u16* Vd,
                                           int tid, int wave) {
#pragma unroll
  for (int i = 0; i < 2; ++i) {
    int n = i * 256 + tid;
    int r = n >> 3, cl = (n & 7) ^ (r & 7);
    gload_lds16(k1b + (size_t)(key0 + r) * HD + cl * 8, (char*)K1d + (i * 256 + wave * 64) * 16);
    gload_lds16(k2b + (size_t)(key0 + r) * HD + cl * 8, (char*)K2d + (i * 256 + wave * 64) * 16);
  }
#pragma unroll
  for (int i = 0; i < 4; ++i) {
    int n = i * 256 + tid;
    int r = n >> 3, cl = (n & 7) ^ (r & 7);
    gload_lds16(vb + (size_t)r * S_ + key0 + cl * 8, (char*)Vd + (i * 256 + wave * 64) * 16);
  }
}

__global__ __launch_bounds__(256) void attn_kernel(
    const u16* __restrict__ Q1, const u16* __restrict__ Q2,
    const u16* __restrict__ K1g, const u16* __restrict__ K2g,
    const u16* __restrict__ Vt, const float* __restrict__ scal,
    const float* __restrict__ subw, u16* __restrict__ attnb) {
  __shared__ u16 K1s[2][64 * 64];
  __shared__ u16 K2s[2][64 * 64];
  __shared__ u16 Vts[2][128 * 64];
  __shared__ u16 Ps[4][16 * 64];
  const int qb = blockIdx.x, h = blockIdx.y, b = blockIdx.z;
  const int tid = threadIdx.x;
  const int wave = tid >> 6, lane = tid & 63;
  const int lr = lane & 15, lkq = (lane >> 4) * 8;
  const int crow = (lane >> 4) * 4;
  const int kv = h >> 1;
  const int keybase = (h & 1) * 1024;   // buggy-repeat dedup: head h attends keys [keybase, keybase+1024)

  const int srow = qb * 64 + wave * 16 + lr;
  const u16* q1p = Q1 + (((size_t)b * NH + h) * S_ + srow) * HD + lkq;
  const u16* q2p = Q2 + (((size_t)b * NH + h) * S_ + srow) * HD + lkq;
  bf16x8v q1f[2], q2f[2];
  q1f[0] = *(const bf16x8v*)(q1p);       q1f[1] = *(const bf16x8v*)(q1p + 32);
  q2f[0] = *(const bf16x8v*)(q2p);       q2f[1] = *(const bf16x8v*)(q2p + 32);

  f32x4 O1[8] = {}, O2[8] = {};
  float m1[4], l1[4], m2[4], l2[4];
#pragma unroll
  for (int j = 0; j < 4; ++j) { m1[j] = -1e30f; l1[j] = 0.f; m2[j] = -1e30f; l2[j] = 0.f; }

  const u16* k1b = K1g + ((size_t)b * NKV + kv) * S_ * HD;
  const u16* k2b = K2g + ((size_t)b * NKV + kv) * S_ * HD;
  const u16* vb  = Vt  + ((size_t)b * NKV + kv) * 128 * S_;

  // 2-phase pipeline: prologue stage(0); per-iter: barrier -> stage(t+1 into alt) -> compute(t).
  stage_tile(k1b, k2b, vb, keybase, K1s[0], K2s[0], Vts[0], tid, wave);
  for (int ck = 0; ck < 16; ++ck) {
    const int cur = ck & 1;
    __syncthreads();   // drains stage(ck) vmcnt + fences prev-iter reads of alt buffer
    if (ck < 15)
      stage_tile(k1b, k2b, vb, keybase + (ck + 1) * 64,
                 K1s[cur ^ 1], K2s[cur ^ 1], Vts[cur ^ 1], tid, wave);
    attn_step(K1s[cur], Vts[cur], Ps[wave], q1f, m1, l1, O1, lane);
    attn_step(K2s[cur], Vts[cur], Ps[wave], q2f, m2, l2, O2, lane);
  }

  const float lam = scal[0], ofac = scal[1];
  float ssq[4] = {0.f, 0.f, 0.f, 0.f};
#pragma unroll
  for (int f = 0; f < 8; ++f)
#pragma unroll
    for (int j = 0; j < 4; ++j) {
      float cv = O1[f][j] / l1[j] - lam * (O2[f][j] / l2[j]);
      O1[f][j] = cv;
      ssq[j] += cv * cv;
    }
#pragma unroll
  for (int off = 1; off < 16; off <<= 1)
#pragma unroll
    for (int j = 0; j < 4; ++j) ssq[j] += __shfl_xor(ssq[j], off);
  float rs[4];
#pragma unroll
  for (int j = 0; j < 4; ++j) rs[j] = rsqrtf(ssq[j] * (1.f / 128.f) + EPS_) * ofac;
  const size_t rowb = (size_t)b * S_ + qb * 64 + wave * 16 + crow;
#pragma unroll
  for (int f = 0; f < 8; ++f) {
    float sw = subw[f * 16 + lr];
#pragma unroll
    for (int j = 0; j < 4; ++j)
      attnb[(rowb + j) * DIM + h * 128 + f * 16 + lr] = bfbits(O1[f][j] * rs[j] * sw);
  }
}

// ---------------- host ----------------
extern "C" void kernel_launch(void* const* d_in, const int* in_sizes, int n_in,
                              void* d_out, int out_size, void* d_ws, size_t ws_size,
                              hipStream_t stream) {
  const float* x   = (const float*)d_in[0];
  const float* wq  = (const float*)d_in[1];
  const float* wk  = (const float*)d_in[2];
  const float* wv  = (const float*)d_in[3];
  const float* wo  = (const float*)d_in[4];
  const float* lq1 = (const float*)d_in[5];
  const float* lk1 = (const float*)d_in[6];
  const float* lq2 = (const float*)d_in[7];
  const float* lk2 = (const float*)d_in[8];
  const float* li  = (const float*)d_in[9];
  const float* subw= (const float*)d_in[10];
  const float* fc  = (const float*)d_in[11];
  const float* fs  = (const float*)d_in[12];
  float* out = (float*)d_out;

  char* ws = (char*)d_ws;
  size_t off = 0;
  auto alloc = [&](size_t bytes) { char* p = ws + off; off += (bytes + 255) & ~(size_t)255; return p; };
  u16*   xb    = (u16*)alloc((size_t)ROWS * DIM * 2);
  u16*   wqkvT = (u16*)alloc((size_t)NQKV * DIM * 2);
  u16*   woT   = (u16*)alloc((size_t)DIM * DIM * 2);
  float* qkv   = (float*)alloc((size_t)ROWS * NQKV * 4);
  u16*   Q1    = (u16*)alloc((size_t)B_ * NH * S_ * HD * 2);
  u16*   Q2    = (u16*)alloc((size_t)B_ * NH * S_ * HD * 2);
  u16*   K1    = (u16*)alloc((size_t)B_ * NKV * S_ * HD * 2);
  u16*   K2    = (u16*)alloc((size_t)B_ * NKV * S_ * HD * 2);
  u16*   Vt    = (u16*)alloc((size_t)B_ * NKV * 128 * S_ * 2);
  u16*   attnb = (u16*)alloc((size_t)ROWS * DIM * 2);
  float* scal  = (float*)alloc(256);

  cast_f32_bf16<<<ROWS * DIM / 4 / 256, 256, 0, stream>>>(x, xb, ROWS * DIM / 4);
  transpose_cast<<<dim3(64, 64), dim3(32, 8), 0, stream>>>(wq, wqkvT, DIM, DIM);
  transpose_cast<<<dim3(32, 64), dim3(32, 8), 0, stream>>>(wk, wqkvT + (size_t)2048 * DIM, DIM, 1024);
  transpose_cast<<<dim3(32, 64), dim3(32, 8), 0, stream>>>(wv, wqkvT + (size_t)3072 * DIM, DIM, 1024);
  transpose_cast<<<dim3(64, 64), dim3(32, 8), 0, stream>>>(wo, woT, DIM, DIM);

  gemm_bt<<<dim3(NQKV / 128, ROWS / 128), 256, 0, stream>>>(xb, wqkvT, qkv, ROWS, NQKV, DIM);

  rope_kernel<<<ROWS * 32 * 32 / 256, 256, 0, stream>>>(qkv, fc, fs, Q1, Q2, 5, 0);
  rope_kernel<<<ROWS * 16 * 32 / 256, 256, 0, stream>>>(qkv, fc, fs, K1, K2, 4, 2048);
  v_transpose<<<dim3(64, 4, 16), dim3(32, 8), 0, stream>>>(qkv, Vt);
  lambda_kernel<<<1, 64, 0, stream>>>(lq1, lk1, lq2, lk2, li, scal);

  attn_kernel<<<dim3(32, NH, B_), 256, 0, stream>>>(Q1, Q2, K1, K2, Vt, scal, subw, attnb);

  gemm_bt<<<dim3(DIM / 128, ROWS / 128), 256, 0, stream>>>(attnb, woT, out, ROWS, DIM, DIM);
}

// Round 6
// 537.804 us; speedup vs baseline: 1.0407x; 1.0407x over previous
//
#include <hip/hip_runtime.h>
#include <stdint.h>

typedef unsigned short u16;
typedef __attribute__((ext_vector_type(8))) short bf16x8v;   // 8 bf16 = 4 VGPR (MFMA A/B frag)
typedef __attribute__((ext_vector_type(4))) float f32x4;     // MFMA C/D frag

#define DIM   2048
#define NH    16
#define NKV   8
#define HD    64
#define B_    2
#define S_    2048
#define ROWS  (B_*S_)     // 4096
#define NQKV  4096
#define EPS_   1e-5f
#define SCALE_ 0.125f     // 64^-0.5

__device__ __forceinline__ u16 bfbits(float f) {
  union { float f; unsigned int u; } a; a.f = f;
  unsigned int u = a.u;
  return (u16)((u + 0x7FFFu + ((u >> 16) & 1u)) >> 16);   // RNE f32->bf16
}

__device__ __forceinline__ f32x4 mfma16(bf16x8v a, bf16x8v b, f32x4 c) {
  return __builtin_amdgcn_mfma_f32_16x16x32_bf16(a, b, c, 0, 0, 0);
}

__device__ __forceinline__ void gload_lds16(const void* g, void* l) {
  __builtin_amdgcn_global_load_lds(
      (const __attribute__((address_space(1))) unsigned int*)g,
      (__attribute__((address_space(3))) unsigned int*)l, 16, 0, 0);
}

// ---------------- elementwise cast x -> bf16 ----------------
__global__ void cast_f32_bf16(const float* __restrict__ src, u16* __restrict__ dst, int n4) {
  int i = blockIdx.x * 256 + threadIdx.x;
  if (i >= n4) return;
  float4 v = ((const float4*)src)[i];
  ushort4 o; o.x = bfbits(v.x); o.y = bfbits(v.y); o.z = bfbits(v.z); o.w = bfbits(v.w);
  ((ushort4*)dst)[i] = o;
}

// ---------------- transpose-cast: src fp32 [R][C] -> dst bf16 [C][R] ----------------
__global__ void transpose_cast(const float* __restrict__ src, u16* __restrict__ dst, int R, int C) {
  __shared__ float t[32][33];
  int c0 = blockIdx.x * 32, r0 = blockIdx.y * 32;
  int x = threadIdx.x, y = threadIdx.y;
#pragma unroll
  for (int i = 0; i < 4; ++i) t[y + 8*i][x] = src[(size_t)(r0 + y + 8*i) * C + c0 + x];
  __syncthreads();
#pragma unroll
  for (int i = 0; i < 4; ++i) dst[(size_t)(c0 + y + 8*i) * R + r0 + x] = bfbits(t[x][y + 8*i]);
}

// ---------------- V transpose: qkv fp32 [row][3072 + kv*128 + dv] -> Vt bf16 [b][kv][dv][s] ----------------
__global__ void v_transpose(const float* __restrict__ qkv, u16* __restrict__ Vt) {
  __shared__ float t[32][33];
  int z = blockIdx.z;                // b*8+kv
  int b = z >> 3, kv = z & 7;
  int s0 = blockIdx.x * 32, d0 = blockIdx.y * 32;
  int x = threadIdx.x, y = threadIdx.y;
  const float* src = qkv + (size_t)b * S_ * NQKV + 3072 + kv * 128;
#pragma unroll
  for (int i = 0; i < 4; ++i) t[y + 8*i][x] = src[(size_t)(s0 + y + 8*i) * NQKV + d0 + x];
  __syncthreads();
  u16* dst = Vt + ((size_t)(b * NKV + kv) * 128) * S_;
#pragma unroll
  for (int i = 0; i < 4; ++i) dst[(size_t)(d0 + y + 8*i) * S_ + s0 + x] = bfbits(t[x][y + 8*i]);
}

// ---------------- RoPE (interleaved) + split comps, fp32 in / bf16 out ----------------
// q: hshift=5 (32 rope-heads), coloff=0, D1/D2 have 16 heads.  k: hshift=4, coloff=2048, 8 heads.
__global__ void rope_kernel(const float* __restrict__ qkv, const float* __restrict__ fc,
                            const float* __restrict__ fs, u16* __restrict__ D1, u16* __restrict__ D2,
                            int hshift, int coloff) {
  int p = blockIdx.x * 256 + threadIdx.x;
  int i = p & 31;
  int hh = (p >> 5) & ((1 << hshift) - 1);
  int row = p >> (5 + hshift);
  int s = row & (S_ - 1);
  int b = row >> 11;
  const float* src = qkv + (size_t)row * NQKV + coloff + hh * HD + 2 * i;
  float e = src[0], o = src[1];
  float c = fc[s * 32 + i], sn = fs[s * 32 + i];
  float r0 = e * c - o * sn, r1 = e * sn + o * c;
  u16* dst = (hh & 1) ? D2 : D1;
  int nh = 1 << (hshift - 1);
  size_t offo = (((size_t)b * nh + (hh >> 1)) * S_ + s) * HD + 2 * i;
  unsigned int packed = (unsigned int)bfbits(r0) | ((unsigned int)bfbits(r1) << 16);
  *(unsigned int*)(dst + offo) = packed;
}

// ---------------- lambda scalars ----------------
__global__ void lambda_kernel(const float* lq1, const float* lk1, const float* lq2,
                              const float* lk2, const float* li, float* scal) {
  int t = threadIdx.x;   // 64
  float p1 = lq1[t] * lk1[t];
  float p2 = lq2[t] * lk2[t];
#pragma unroll
  for (int off = 32; off > 0; off >>= 1) { p1 += __shfl_xor(p1, off); p2 += __shfl_xor(p2, off); }
  if (t == 0) {
    scal[0] = __expf(p1) - __expf(p2) + li[0];  // lambda_full
    scal[1] = 1.0f - li[0];                     // output scale
  }
}

// ---------------- GEMM: C fp32 [M][N] = A bf16 [M][K] @ Bt bf16 [N][K]^T ----------------
__global__ __launch_bounds__(256) void gemm_bt(const u16* __restrict__ A, const u16* __restrict__ Bt,
                                               float* __restrict__ C, int M, int N, int K) {
  __shared__ u16 As[128 * 32];
  __shared__ u16 Bs[128 * 32];
  const int tid = threadIdx.x;
  const int wave = tid >> 6, lane = tid & 63;
  const int lr = lane & 15, lk = (lane >> 4) * 8;
  const size_t row0 = (size_t)blockIdx.y * 128, col0 = (size_t)blockIdx.x * 128;
  const int wr = (wave >> 1) * 64, wc = (wave & 1) * 64;
  f32x4 acc[4][4] = {};
  for (int kt = 0; kt < K; kt += 32) {
#pragma unroll
    for (int i = 0; i < 2; ++i) {
      int c = i * 256 + tid;
      int r = c >> 2, c8 = (c & 3) * 8;
      gload_lds16(A  + (row0 + r) * (size_t)K + kt + c8, (char*)As + (i * 256 + wave * 64) * 16);
      gload_lds16(Bt + (col0 + r) * (size_t)K + kt + c8, (char*)Bs + (i * 256 + wave * 64) * 16);
    }
    __syncthreads();
    bf16x8v af[4], bv[4];
#pragma unroll
    for (int m = 0; m < 4; ++m) af[m] = *(const bf16x8v*)(As + (wr + m * 16 + lr) * 32 + lk);
#pragma unroll
    for (int n = 0; n < 4; ++n) bv[n] = *(const bf16x8v*)(Bs + (wc + n * 16 + lr) * 32 + lk);
#pragma unroll
    for (int m = 0; m < 4; ++m)
#pragma unroll
      for (int n = 0; n < 4; ++n) acc[m][n] = mfma16(af[m], bv[n], acc[m][n]);
    __syncthreads();
  }
  const int crow = (lane >> 4) * 4;
#pragma unroll
  for (int m = 0; m < 4; ++m)
#pragma unroll
    for (int n = 0; n < 4; ++n) {
      float* cp = C + (row0 + wr + m * 16 + crow) * (size_t)N + col0 + wc + n * 16 + lr;
#pragma unroll
      for (int j = 0; j < 4; ++j) cp[(size_t)j * N] = acc[m][n][j];
    }
}

// ---------------- fused differential attention ----------------
// All LDS tiles are [rows][8 chunks of 16B] with XOR swizzle: physical chunk
// c_phys at row r holds logical chunk c_phys ^ (r&7). Staged via per-lane
// pre-swizzled global source (rule #21); every ds_read applies c ^ (r&7).
// Both attention components are processed INTERLEAVED in one step: the kernel
// is latency-bound (2 waves/SIMD), so comp1/comp2 provide mutual ILP, and V
// fragments are read from LDS once for both PV accumulations.
__device__ __forceinline__ void attn_step2(const u16* K1, const u16* K2, const u16* Vts,
                                           u16* Pw1, u16* Pw2,
                                           const bf16x8v* q1f, const bf16x8v* q2f,
                                           float* m1, float* l1, f32x4* O1,
                                           float* m2, float* l2, f32x4* O2,
                                           int lane) {
  const int lr = lane & 15, cq = lane >> 4, crow = cq * 4;
  f32x4 s1[4] = {}, s2[4] = {};
  __builtin_amdgcn_s_setprio(1);
#pragma unroll
  for (int kf = 0; kf < 4; ++kf) {
    const int row = kf * 16 + lr, sw = row & 7;
    const bf16x8v ka0 = *(const bf16x8v*)(K1 + row * 64 + ((cq ^ sw) * 8));
    const bf16x8v ka1 = *(const bf16x8v*)(K1 + row * 64 + (((cq + 4) ^ sw) * 8));
    const bf16x8v kb0 = *(const bf16x8v*)(K2 + row * 64 + ((cq ^ sw) * 8));
    const bf16x8v kb1 = *(const bf16x8v*)(K2 + row * 64 + (((cq + 4) ^ sw) * 8));
    s1[kf] = mfma16(q1f[0], ka0, s1[kf]);
    s2[kf] = mfma16(q2f[0], kb0, s2[kf]);
    s1[kf] = mfma16(q1f[1], ka1, s1[kf]);
    s2[kf] = mfma16(q2f[1], kb1, s2[kf]);
  }
  __builtin_amdgcn_s_setprio(0);
  float pm1[4], pm2[4];
#pragma unroll
  for (int j = 0; j < 4; ++j) { pm1[j] = -1e30f; pm2[j] = -1e30f; }
#pragma unroll
  for (int kf = 0; kf < 4; ++kf)
#pragma unroll
    for (int j = 0; j < 4; ++j) {
      float a = s1[kf][j] * SCALE_, b = s2[kf][j] * SCALE_;
      s1[kf][j] = a; s2[kf][j] = b;
      pm1[j] = fmaxf(pm1[j], a); pm2[j] = fmaxf(pm2[j], b);
    }
#pragma unroll
  for (int off = 1; off < 16; off <<= 1)
#pragma unroll
    for (int j = 0; j < 4; ++j) {
      pm1[j] = fmaxf(pm1[j], __shfl_xor(pm1[j], off));
      pm2[j] = fmaxf(pm2[j], __shfl_xor(pm2[j], off));
    }
  float al1[4], al2[4], ps1[4], ps2[4];
#pragma unroll
  for (int j = 0; j < 4; ++j) {
    float mn1 = fmaxf(m1[j], pm1[j]), mn2 = fmaxf(m2[j], pm2[j]);
    al1[j] = __expf(m1[j] - mn1);     al2[j] = __expf(m2[j] - mn2);
    m1[j] = mn1;                      m2[j] = mn2;
    ps1[j] = 0.f;                     ps2[j] = 0.f;
  }
#pragma unroll
  for (int kf = 0; kf < 4; ++kf)
#pragma unroll
    for (int j = 0; j < 4; ++j) {
      float p1 = __expf(s1[kf][j] - m1[j]);
      float p2 = __expf(s2[kf][j] - m2[j]);
      s1[kf][j] = p1; s2[kf][j] = p2;
      ps1[j] += p1;   ps2[j] += p2;
    }
#pragma unroll
  for (int off = 1; off < 16; off <<= 1)
#pragma unroll
    for (int j = 0; j < 4; ++j) {
      ps1[j] += __shfl_xor(ps1[j], off);
      ps2[j] += __shfl_xor(ps2[j], off);
    }
#pragma unroll
  for (int j = 0; j < 4; ++j) {
    l1[j] = l1[j] * al1[j] + ps1[j];
    l2[j] = l2[j] * al2[j] + ps2[j];
  }
#pragma unroll
  for (int f = 0; f < 8; ++f)
#pragma unroll
    for (int j = 0; j < 4; ++j) { O1[f][j] *= al1[j]; O2[f][j] *= al2[j]; }
  // P (C-layout) -> LDS (swizzled) so it can be re-read in A-layout
#pragma unroll
  for (int kf = 0; kf < 4; ++kf) {
    const int ch = kf * 2 + (lr >> 3), cl = lr & 7;   // col = kf*16+lr -> chunk, within-chunk
#pragma unroll
    for (int j = 0; j < 4; ++j) {
      const int row = crow + j;
      const int o = row * 64 + ((ch ^ (row & 7)) * 8) + cl;
      Pw1[o] = bfbits(s1[kf][j]);
      Pw2[o] = bfbits(s2[kf][j]);
    }
  }
  __builtin_amdgcn_s_setprio(1);
#pragma unroll
  for (int kst = 0; kst < 2; ++kst) {
    const int po = lr * 64 + (((kst * 4 + cq) ^ (lr & 7)) * 8);
    bf16x8v pf1 = *(const bf16x8v*)(Pw1 + po);
    bf16x8v pf2 = *(const bf16x8v*)(Pw2 + po);
#pragma unroll
    for (int f = 0; f < 8; ++f) {
      const int row = f * 16 + lr;
      bf16x8v vf = *(const bf16x8v*)(Vts + row * 64 + (((kst * 4 + cq) ^ (row & 7)) * 8));
      O1[f] = mfma16(pf1, vf, O1[f]);
      O2[f] = mfma16(pf2, vf, O2[f]);
    }
  }
  __builtin_amdgcn_s_setprio(0);
}

__device__ __forceinline__ void stage_tile(const u16* k1b, const u16* k2b, const u16* vb,
                                           int key0, u16* K1d, u16* K2d, u16* Vd,
                                           int tid, int wave) {
#pragma unroll
  for (int i = 0; i < 2; ++i) {
    int n = i * 256 + tid;
    int r = n >> 3, cl = (n & 7) ^ (r & 7);
    gload_lds16(k1b + (size_t)(key0 + r) * HD + cl * 8, (char*)K1d + (i * 256 + wave * 64) * 16);
    gload_lds16(k2b + (size_t)(key0 + r) * HD + cl * 8, (char*)K2d + (i * 256 + wave * 64) * 16);
  }
#pragma unroll
  for (int i = 0; i < 4; ++i) {
    int n = i * 256 + tid;
    int r = n >> 3, cl = (n & 7) ^ (r & 7);
    gload_lds16(vb + (size_t)r * S_ + key0 + cl * 8, (char*)Vd + (i * 256 + wave * 64) * 16);
  }
}

__global__ __launch_bounds__(256) void attn_kernel(
    const u16* __restrict__ Q1, const u16* __restrict__ Q2,
    const u16* __restrict__ K1g, const u16* __restrict__ K2g,
    const u16* __restrict__ Vt, const float* __restrict__ scal,
    const float* __restrict__ subw, u16* __restrict__ attnb) {
  __shared__ u16 K1s[2][64 * 64];
  __shared__ u16 K2s[2][64 * 64];
  __shared__ u16 Vts[2][128 * 64];
  __shared__ u16 Ps1[4][16 * 64];
  __shared__ u16 Ps2[4][16 * 64];
  const int qb = blockIdx.x, h = blockIdx.y, b = blockIdx.z;
  const int tid = threadIdx.x;
  const int wave = tid >> 6, lane = tid & 63;
  const int lr = lane & 15, lkq = (lane >> 4) * 8;
  const int crow = (lane >> 4) * 4;
  const int kv = h >> 1;
  const int keybase = (h & 1) * 1024;   // buggy-repeat dedup: head h attends keys [keybase, keybase+1024)

  const int srow = qb * 64 + wave * 16 + lr;
  const u16* q1p = Q1 + (((size_t)b * NH + h) * S_ + srow) * HD + lkq;
  const u16* q2p = Q2 + (((size_t)b * NH + h) * S_ + srow) * HD + lkq;
  bf16x8v q1f[2], q2f[2];
  q1f[0] = *(const bf16x8v*)(q1p);       q1f[1] = *(const bf16x8v*)(q1p + 32);
  q2f[0] = *(const bf16x8v*)(q2p);       q2f[1] = *(const bf16x8v*)(q2p + 32);

  f32x4 O1[8] = {}, O2[8] = {};
  float m1[4], l1[4], m2[4], l2[4];
#pragma unroll
  for (int j = 0; j < 4; ++j) { m1[j] = -1e30f; l1[j] = 0.f; m2[j] = -1e30f; l2[j] = 0.f; }

  const u16* k1b = K1g + ((size_t)b * NKV + kv) * S_ * HD;
  const u16* k2b = K2g + ((size_t)b * NKV + kv) * S_ * HD;
  const u16* vb  = Vt  + ((size_t)b * NKV + kv) * 128 * S_;

  // 2-phase pipeline: prologue stage(0); per-iter: barrier -> stage(t+1 into alt) -> compute(t).
  stage_tile(k1b, k2b, vb, keybase, K1s[0], K2s[0], Vts[0], tid, wave);
  for (int ck = 0; ck < 16; ++ck) {
    const int cur = ck & 1;
    __syncthreads();   // drains stage(ck) vmcnt + fences prev-iter reads of alt buffer
    if (ck < 15)
      stage_tile(k1b, k2b, vb, keybase + (ck + 1) * 64,
                 K1s[cur ^ 1], K2s[cur ^ 1], Vts[cur ^ 1], tid, wave);
    attn_step2(K1s[cur], K2s[cur], Vts[cur], Ps1[wave], Ps2[wave],
               q1f, q2f, m1, l1, O1, m2, l2, O2, lane);
  }

  const float lam = scal[0], ofac = scal[1];
  float ssq[4] = {0.f, 0.f, 0.f, 0.f};
#pragma unroll
  for (int f = 0; f < 8; ++f)
#pragma unroll
    for (int j = 0; j < 4; ++j) {
      float cv = O1[f][j] / l1[j] - lam * (O2[f][j] / l2[j]);
      O1[f][j] = cv;
      ssq[j] += cv * cv;
    }
#pragma unroll
  for (int off = 1; off < 16; off <<= 1)
#pragma unroll
    for (int j = 0; j < 4; ++j) ssq[j] += __shfl_xor(ssq[j], off);
  float rs[4];
#pragma unroll
  for (int j = 0; j < 4; ++j) rs[j] = rsqrtf(ssq[j] * (1.f / 128.f) + EPS_) * ofac;
  const size_t rowb = (size_t)b * S_ + qb * 64 + wave * 16 + crow;
#pragma unroll
  for (int f = 0; f < 8; ++f) {
    float sw = subw[f * 16 + lr];
#pragma unroll
    for (int j = 0; j < 4; ++j)
      attnb[(rowb + j) * DIM + h * 128 + f * 16 + lr] = bfbits(O1[f][j] * rs[j] * sw);
  }
}

// ---------------- host ----------------
extern "C" void kernel_launch(void* const* d_in, const int* in_sizes, int n_in,
                              void* d_out, int out_size, void* d_ws, size_t ws_size,
                              hipStream_t stream) {
  const float* x   = (const float*)d_in[0];
  const float* wq  = (const float*)d_in[1];
  const float* wk  = (const float*)d_in[2];
  const float* wv  = (const float*)d_in[3];
  const float* wo  = (const float*)d_in[4];
  const float* lq1 = (const float*)d_in[5];
  const float* lk1 = (const float*)d_in[6];
  const float* lq2 = (const float*)d_in[7];
  const float* lk2 = (const float*)d_in[8];
  const float* li  = (const float*)d_in[9];
  const float* subw= (const float*)d_in[10];
  const float* fc  = (const float*)d_in[11];
  const float* fs  = (const float*)d_in[12];
  float* out = (float*)d_out;

  char* ws = (char*)d_ws;
  size_t off = 0;
  auto alloc = [&](size_t bytes) { char* p = ws + off; off += (bytes + 255) & ~(size_t)255; return p; };
  u16*   xb    = (u16*)alloc((size_t)ROWS * DIM * 2);
  u16*   wqkvT = (u16*)alloc((size_t)NQKV * DIM * 2);
  u16*   woT   = (u16*)alloc((size_t)DIM * DIM * 2);
  float* qkv   = (float*)alloc((size_t)ROWS * NQKV * 4);
  u16*   Q1    = (u16*)alloc((size_t)B_ * NH * S_ * HD * 2);
  u16*   Q2    = (u16*)alloc((size_t)B_ * NH * S_ * HD * 2);
  u16*   K1    = (u16*)alloc((size_t)B_ * NKV * S_ * HD * 2);
  u16*   K2    = (u16*)alloc((size_t)B_ * NKV * S_ * HD * 2);
  u16*   Vt    = (u16*)alloc((size_t)B_ * NKV * 128 * S_ * 2);
  u16*   attnb = (u16*)alloc((size_t)ROWS * DIM * 2);
  float* scal  = (float*)alloc(256);

  cast_f32_bf16<<<ROWS * DIM / 4 / 256, 256, 0, stream>>>(x, xb, ROWS * DIM / 4);
  transpose_cast<<<dim3(64, 64), dim3(32, 8), 0, stream>>>(wq, wqkvT, DIM, DIM);
  transpose_cast<<<dim3(32, 64), dim3(32, 8), 0, stream>>>(wk, wqkvT + (size_t)2048 * DIM, DIM, 1024);
  transpose_cast<<<dim3(32, 64), dim3(32, 8), 0, stream>>>(wv, wqkvT + (size_t)3072 * DIM, DIM, 1024);
  transpose_cast<<<dim3(64, 64), dim3(32, 8), 0, stream>>>(wo, woT, DIM, DIM);

  gemm_bt<<<dim3(NQKV / 128, ROWS / 128), 256, 0, stream>>>(xb, wqkvT, qkv, ROWS, NQKV, DIM);

  rope_kernel<<<ROWS * 32 * 32 / 256, 256, 0, stream>>>(qkv, fc, fs, Q1, Q2, 5, 0);
  rope_kernel<<<ROWS * 16 * 32 / 256, 256, 0, stream>>>(qkv, fc, fs, K1, K2, 4, 2048);
  v_transpose<<<dim3(64, 4, 16), dim3(32, 8), 0, stream>>>(qkv, Vt);
  lambda_kernel<<<1, 64, 0, stream>>>(lq1, lk1, lq2, lk2, li, scal);

  attn_kernel<<<dim3(32, NH, B_), 256, 0, stream>>>(Q1, Q2, K1, K2, Vt, scal, subw, attnb);

  gemm_bt<<<dim3(DIM / 128, ROWS / 128), 256, 0, stream>>>(attnb, woT, out, ROWS, DIM, DIM);
}

// Round 8
// 495.088 us; speedup vs baseline: 1.1305x; 1.0863x over previous
//
#include <hip/hip_runtime.h>
#include <stdint.h>

typedef unsigned short u16;
typedef __attribute__((ext_vector_type(8))) short bf16x8v;   // 8 bf16 = 4 VGPR (MFMA A/B frag)
typedef __attribute__((ext_vector_type(4))) float f32x4;     // MFMA C/D frag

#define DIM   2048
#define NH    16
#define NKV   8
#define HD    64
#define B_    2
#define S_    2048
#define ROWS  (B_*S_)     // 4096
#define NQKV  4096
#define EPS_   1e-5f
#define SCALE_ 0.125f     // 64^-0.5

__device__ __forceinline__ u16 bfbits(float f) {
  union { float f; unsigned int u; } a; a.f = f;
  unsigned int u = a.u;
  return (u16)((u + 0x7FFFu + ((u >> 16) & 1u)) >> 16);   // RNE f32->bf16
}

__device__ __forceinline__ f32x4 mfma16(bf16x8v a, bf16x8v b, f32x4 c) {
  return __builtin_amdgcn_mfma_f32_16x16x32_bf16(a, b, c, 0, 0, 0);
}

__device__ __forceinline__ void gload_lds16(const void* g, void* l) {
  __builtin_amdgcn_global_load_lds(
      (const __attribute__((address_space(1))) unsigned int*)g,
      (__attribute__((address_space(3))) unsigned int*)l, 16, 0, 0);
}

// ---------------- elementwise cast x -> bf16 ----------------
__global__ void cast_f32_bf16(const float* __restrict__ src, u16* __restrict__ dst, int n4) {
  int i = blockIdx.x * 256 + threadIdx.x;
  if (i >= n4) return;
  float4 v = ((const float4*)src)[i];
  ushort4 o; o.x = bfbits(v.x); o.y = bfbits(v.y); o.z = bfbits(v.z); o.w = bfbits(v.w);
  ((ushort4*)dst)[i] = o;
}

// ---------------- transpose-cast: src fp32 [R][C] -> dst bf16 [C][R] ----------------
__global__ void transpose_cast(const float* __restrict__ src, u16* __restrict__ dst, int R, int C) {
  __shared__ float t[32][33];
  int c0 = blockIdx.x * 32, r0 = blockIdx.y * 32;
  int x = threadIdx.x, y = threadIdx.y;
#pragma unroll
  for (int i = 0; i < 4; ++i) t[y + 8*i][x] = src[(size_t)(r0 + y + 8*i) * C + c0 + x];
  __syncthreads();
#pragma unroll
  for (int i = 0; i < 4; ++i) dst[(size_t)(c0 + y + 8*i) * R + r0 + x] = bfbits(t[x][y + 8*i]);
}

// ---------------- V transpose: qkv fp32 [row][3072 + kv*128 + dv] -> Vt bf16 [b][kv][dv][s] ----------------
__global__ void v_transpose(const float* __restrict__ qkv, u16* __restrict__ Vt) {
  __shared__ float t[32][33];
  int z = blockIdx.z;                // b*8+kv
  int b = z >> 3, kv = z & 7;
  int s0 = blockIdx.x * 32, d0 = blockIdx.y * 32;
  int x = threadIdx.x, y = threadIdx.y;
  const float* src = qkv + (size_t)b * S_ * NQKV + 3072 + kv * 128;
#pragma unroll
  for (int i = 0; i < 4; ++i) t[y + 8*i][x] = src[(size_t)(s0 + y + 8*i) * NQKV + d0 + x];
  __syncthreads();
  u16* dst = Vt + ((size_t)(b * NKV + kv) * 128) * S_;
#pragma unroll
  for (int i = 0; i < 4; ++i) dst[(size_t)(d0 + y + 8*i) * S_ + s0 + x] = bfbits(t[x][y + 8*i]);
}

// ---------------- RoPE (interleaved) + split comps, fp32 in / bf16 out ----------------
// q: hshift=5 (32 rope-heads), coloff=0, D1/D2 have 16 heads.  k: hshift=4, coloff=2048, 8 heads.
__global__ void rope_kernel(const float* __restrict__ qkv, const float* __restrict__ fc,
                            const float* __restrict__ fs, u16* __restrict__ D1, u16* __restrict__ D2,
                            int hshift, int coloff) {
  int p = blockIdx.x * 256 + threadIdx.x;
  int i = p & 31;
  int hh = (p >> 5) & ((1 << hshift) - 1);
  int row = p >> (5 + hshift);
  int s = row & (S_ - 1);
  int b = row >> 11;
  const float* src = qkv + (size_t)row * NQKV + coloff + hh * HD + 2 * i;
  float e = src[0], o = src[1];
  float c = fc[s * 32 + i], sn = fs[s * 32 + i];
  float r0 = e * c - o * sn, r1 = e * sn + o * c;
  u16* dst = (hh & 1) ? D2 : D1;
  int nh = 1 << (hshift - 1);
  size_t offo = (((size_t)b * nh + (hh >> 1)) * S_ + s) * HD + 2 * i;
  unsigned int packed = (unsigned int)bfbits(r0) | ((unsigned int)bfbits(r1) << 16);
  *(unsigned int*)(dst + offo) = packed;
}

// ---------------- lambda scalars ----------------
__global__ void lambda_kernel(const float* lq1, const float* lk1, const float* lq2,
                              const float* lk2, const float* li, float* scal) {
  int t = threadIdx.x;   // 64
  float p1 = lq1[t] * lk1[t];
  float p2 = lq2[t] * lk2[t];
#pragma unroll
  for (int off = 32; off > 0; off >>= 1) { p1 += __shfl_xor(p1, off); p2 += __shfl_xor(p2, off); }
  if (t == 0) {
    scal[0] = __expf(p1) - __expf(p2) + li[0];  // lambda_full
    scal[1] = 1.0f - li[0];                     // output scale
  }
}

// ---------------- 8-phase 256-row GEMM: C fp32 [M][N] = A bf16 [M][K] @ Bt bf16 [N][K]^T ----------
// BM=256, BK=64, 512 threads = 8 waves (2M x 4N). NI = n-frags/wave: 4 -> BN=256, 2 -> BN=128.
// 2 K-tiles per iteration, double-buffered LDS (even tiles buf0, odd buf1), chunk^=(row&7) swizzle
// (linear global_load_lds dest + inverse-swizzled global src). Counted vmcnt(4/2) at ph4/ph8 only.
// Region safety: B staged only in B-read-free phases (3,7); A staged only in A-read-free (2,6);
// b0 frags held in regs so ph4/ph8 issue no ds_reads.
template<int NI>
__global__ __launch_bounds__(512, 2) void gemm8p(const u16* __restrict__ A, const u16* __restrict__ Bt,
                                                 float* __restrict__ C, int M, int N, int K) {
  constexpr int BN = NI * 64;
  constexpr int BROUNDS = BN / 64;           // staging rounds for one B K-tile
  __shared__ u16 Al[2][256 * 64];
  __shared__ u16 Bl[2][BN * 64];
  const int tid = threadIdx.x;
  const int wid = tid >> 6, lane = tid & 63;
  const int wm = wid >> 2, wn = wid & 3;
  const int lr = lane & 15, cq = lane >> 4;
  const size_t row0 = (size_t)blockIdx.y * 256, col0 = (size_t)blockIdx.x * BN;

  f32x4 acc[8][NI];
#pragma unroll
  for (int i = 0; i < 8; ++i)
#pragma unroll
    for (int j = 0; j < NI; ++j) acc[i][j] = f32x4{0.f, 0.f, 0.f, 0.f};

  bf16x8v a[4][2], b0[NI / 2][2], b1[NI / 2][2];

  auto stageA = [&](int buf, int kt) {
#pragma unroll
    for (int rd = 0; rd < 4; ++rd) {
      int n = rd * 512 + tid;
      int r = n >> 3, c = (n & 7) ^ (r & 7);
      gload_lds16(A + (row0 + r) * (size_t)K + kt + c * 8,
                  (char*)&Al[buf][0] + (rd * 512 + wid * 64) * 16);
    }
  };
  auto stageB = [&](int buf, int kt) {
#pragma unroll
    for (int rd = 0; rd < BROUNDS; ++rd) {
      int n = rd * 512 + tid;
      int r = n >> 3, c = (n & 7) ^ (r & 7);
      gload_lds16(Bt + (col0 + r) * (size_t)K + kt + c * 8,
                  (char*)&Bl[buf][0] + (rd * 512 + wid * 64) * 16);
    }
  };
  auto readA = [&](int buf, int mh) {
#pragma unroll
    for (int m2 = 0; m2 < 4; ++m2)
#pragma unroll
      for (int ks = 0; ks < 2; ++ks) {
        int rt = wm * 128 + (mh * 4 + m2) * 16 + lr;
        a[m2][ks] = *(const bf16x8v*)&Al[buf][rt * 64 + (((ks * 4 + cq) ^ (rt & 7)) * 8)];
      }
  };
  auto readB = [&](int buf, int nh, bf16x8v (&bb)[NI / 2][2]) {
#pragma unroll
    for (int n2 = 0; n2 < NI / 2; ++n2)
#pragma unroll
      for (int ks = 0; ks < 2; ++ks) {
        int rt = wn * (NI * 16) + (nh * (NI / 2) + n2) * 16 + lr;
        bb[n2][ks] = *(const bf16x8v*)&Bl[buf][rt * 64 + (((ks * 4 + cq) ^ (rt & 7)) * 8)];
      }
  };
  auto mfmaq = [&](int mh, int nh, bf16x8v (&bb)[NI / 2][2]) {
    __builtin_amdgcn_s_barrier();
    asm volatile("s_waitcnt lgkmcnt(0)" ::: "memory");
    __builtin_amdgcn_sched_barrier(0);
    __builtin_amdgcn_s_setprio(1);
#pragma unroll
    for (int m2 = 0; m2 < 4; ++m2)
#pragma unroll
      for (int n2 = 0; n2 < NI / 2; ++n2)
#pragma unroll
        for (int ks = 0; ks < 2; ++ks)
          acc[mh * 4 + m2][nh * (NI / 2) + n2] =
              mfma16(a[m2][ks], bb[n2][ks], acc[mh * 4 + m2][nh * (NI / 2) + n2]);
    __builtin_amdgcn_s_setprio(0);
    __builtin_amdgcn_s_barrier();
  };
  auto vmwait = [&](bool last) {
    if (last) { asm volatile("s_waitcnt vmcnt(0)" ::: "memory"); }
    else {
      if constexpr (NI == 4) { asm volatile("s_waitcnt vmcnt(4)" ::: "memory"); }
      else                   { asm volatile("s_waitcnt vmcnt(2)" ::: "memory"); }
    }
  };

  // Prologue: tile0 (A+B -> buf0), B of tile1 -> buf1. A(t1) is staged at ph2 of iter0.
  stageA(0, 0);
  stageB(0, 0);
  stageB(1, 64);
  vmwait(false);                 // tile0 landed; B(t1) stays in flight
  __builtin_amdgcn_s_barrier();

  const int NITER = K >> 7;      // 2 tiles of BK=64 per iteration
  for (int it = 0; it < NITER; ++it) {
    const int kt = it << 7;
    const bool nl = (it < NITER - 1);
    // ph1: reads tile t (buf0) A-half0 + B-half0
    readA(0, 0); readB(0, 0, b0);
    mfmaq(0, 0, b0);
    // ph2: reads B-half1; stage A(t+1) -> buf1 (A-free phase)
    readB(0, 1, b1);
    stageA(1, kt + 64);
    mfmaq(0, 1, b1);
    // ph3: reads A-half1; stage B(t+2) -> buf0 (B-free phase)
    readA(0, 1);
    if (nl) stageB(0, kt + 128);
    mfmaq(1, 1, b1);
    // ph4: no reads (b0 kept); counted vmcnt -> t+1 ready
    vmwait(!nl);
    mfmaq(1, 0, b0);
    // ph5: reads tile t+1 (buf1) A-half0 + B-half0
    readA(1, 0); readB(1, 0, b0);
    mfmaq(0, 0, b0);
    // ph6: reads B-half1; stage A(t+2) -> buf0
    readB(1, 1, b1);
    if (nl) stageA(0, kt + 128);
    mfmaq(0, 1, b1);
    // ph7: reads A-half1; stage B(t+3) -> buf1
    readA(1, 1);
    if (nl) stageB(1, kt + 192);
    mfmaq(1, 1, b1);
    // ph8: counted vmcnt -> t+2 ready
    vmwait(!nl);
    mfmaq(1, 0, b0);
  }

  const int crow = cq * 4;
#pragma unroll
  for (int mi = 0; mi < 8; ++mi)
#pragma unroll
    for (int ni = 0; ni < NI; ++ni) {
      float* cp = C + (row0 + wm * 128 + mi * 16 + crow) * (size_t)N + col0 + wn * (NI * 16) + ni * 16 + lr;
#pragma unroll
      for (int j = 0; j < 4; ++j) cp[(size_t)j * N] = acc[mi][ni][j];
    }
}

// ---------------- fused differential attention ----------------
// All LDS tiles are [rows][8 chunks of 16B] with XOR swizzle: physical chunk
// c_phys at row r holds logical chunk c_phys ^ (r&7). Staged via per-lane
// pre-swizzled global source (rule #21); every ds_read applies c ^ (r&7).
// Both attention components are processed INTERLEAVED in one step: the kernel
// is latency-bound (2 waves/SIMD), so comp1/comp2 provide mutual ILP, and V
// fragments are read from LDS once for both PV accumulations.
__device__ __forceinline__ void attn_step2(const u16* K1, const u16* K2, const u16* Vts,
                                           u16* Pw1, u16* Pw2,
                                           const bf16x8v* q1f, const bf16x8v* q2f,
                                           float* m1, float* l1, f32x4* O1,
                                           float* m2, float* l2, f32x4* O2,
                                           int lane) {
  const int lr = lane & 15, cq = lane >> 4, crow = cq * 4;
  f32x4 s1[4] = {}, s2[4] = {};
  __builtin_amdgcn_s_setprio(1);
#pragma unroll
  for (int kf = 0; kf < 4; ++kf) {
    const int row = kf * 16 + lr, sw = row & 7;
    const bf16x8v ka0 = *(const bf16x8v*)(K1 + row * 64 + ((cq ^ sw) * 8));
    const bf16x8v ka1 = *(const bf16x8v*)(K1 + row * 64 + (((cq + 4) ^ sw) * 8));
    const bf16x8v kb0 = *(const bf16x8v*)(K2 + row * 64 + ((cq ^ sw) * 8));
    const bf16x8v kb1 = *(const bf16x8v*)(K2 + row * 64 + (((cq + 4) ^ sw) * 8));
    s1[kf] = mfma16(q1f[0], ka0, s1[kf]);
    s2[kf] = mfma16(q2f[0], kb0, s2[kf]);
    s1[kf] = mfma16(q1f[1], ka1, s1[kf]);
    s2[kf] = mfma16(q2f[1], kb1, s2[kf]);
  }
  __builtin_amdgcn_s_setprio(0);
  float pm1[4], pm2[4];
#pragma unroll
  for (int j = 0; j < 4; ++j) { pm1[j] = -1e30f; pm2[j] = -1e30f; }
#pragma unroll
  for (int kf = 0; kf < 4; ++kf)
#pragma unroll
    for (int j = 0; j < 4; ++j) {
      float a = s1[kf][j] * SCALE_, b = s2[kf][j] * SCALE_;
      s1[kf][j] = a; s2[kf][j] = b;
      pm1[j] = fmaxf(pm1[j], a); pm2[j] = fmaxf(pm2[j], b);
    }
#pragma unroll
  for (int off = 1; off < 16; off <<= 1)
#pragma unroll
    for (int j = 0; j < 4; ++j) {
      pm1[j] = fmaxf(pm1[j], __shfl_xor(pm1[j], off));
      pm2[j] = fmaxf(pm2[j], __shfl_xor(pm2[j], off));
    }
  float al1[4], al2[4], ps1[4], ps2[4];
#pragma unroll
  for (int j = 0; j < 4; ++j) {
    float mn1 = fmaxf(m1[j], pm1[j]), mn2 = fmaxf(m2[j], pm2[j]);
    al1[j] = __expf(m1[j] - mn1);     al2[j] = __expf(m2[j] - mn2);
    m1[j] = mn1;                      m2[j] = mn2;
    ps1[j] = 0.f;                     ps2[j] = 0.f;
  }
#pragma unroll
  for (int kf = 0; kf < 4; ++kf)
#pragma unroll
    for (int j = 0; j < 4; ++j) {
      float p1 = __expf(s1[kf][j] - m1[j]);
      float p2 = __expf(s2[kf][j] - m2[j]);
      s1[kf][j] = p1; s2[kf][j] = p2;
      ps1[j] += p1;   ps2[j] += p2;
    }
#pragma unroll
  for (int off = 1; off < 16; off <<= 1)
#pragma unroll
    for (int j = 0; j < 4; ++j) {
      ps1[j] += __shfl_xor(ps1[j], off);
      ps2[j] += __shfl_xor(ps2[j], off);
    }
#pragma unroll
  for (int j = 0; j < 4; ++j) {
    l1[j] = l1[j] * al1[j] + ps1[j];
    l2[j] = l2[j] * al2[j] + ps2[j];
  }
#pragma unroll
  for (int f = 0; f < 8; ++f)
#pragma unroll
    for (int j = 0; j < 4; ++j) { O1[f][j] *= al1[j]; O2[f][j] *= al2[j]; }
  // P (C-layout) -> LDS (swizzled) so it can be re-read in A-layout
#pragma unroll
  for (int kf = 0; kf < 4; ++kf) {
    const int ch = kf * 2 + (lr >> 3), cl = lr & 7;   // col = kf*16+lr -> chunk, within-chunk
#pragma unroll
    for (int j = 0; j < 4; ++j) {
      const int row = crow + j;
      const int o = row * 64 + ((ch ^ (row & 7)) * 8) + cl;
      Pw1[o] = bfbits(s1[kf][j]);
      Pw2[o] = bfbits(s2[kf][j]);
    }
  }
  __builtin_amdgcn_s_setprio(1);
#pragma unroll
  for (int kst = 0; kst < 2; ++kst) {
    const int po = lr * 64 + (((kst * 4 + cq) ^ (lr & 7)) * 8);
    bf16x8v pf1 = *(const bf16x8v*)(Pw1 + po);
    bf16x8v pf2 = *(const bf16x8v*)(Pw2 + po);
#pragma unroll
    for (int f = 0; f < 8; ++f) {
      const int row = f * 16 + lr;
      bf16x8v vf = *(const bf16x8v*)(Vts + row * 64 + (((kst * 4 + cq) ^ (row & 7)) * 8));
      O1[f] = mfma16(pf1, vf, O1[f]);
      O2[f] = mfma16(pf2, vf, O2[f]);
    }
  }
  __builtin_amdgcn_s_setprio(0);
}

__device__ __forceinline__ void stage_tile(const u16* k1b, const u16* k2b, const u16* vb,
                                           int key0, u16* K1d, u16* K2d, u16* Vd,
                                           int tid, int wave) {
#pragma unroll
  for (int i = 0; i < 2; ++i) {
    int n = i * 256 + tid;
    int r = n >> 3, cl = (n & 7) ^ (r & 7);
    gload_lds16(k1b + (size_t)(key0 + r) * HD + cl * 8, (char*)K1d + (i * 256 + wave * 64) * 16);
    gload_lds16(k2b + (size_t)(key0 + r) * HD + cl * 8, (char*)K2d + (i * 256 + wave * 64) * 16);
  }
#pragma unroll
  for (int i = 0; i < 4; ++i) {
    int n = i * 256 + tid;
    int r = n >> 3, cl = (n & 7) ^ (r & 7);
    gload_lds16(vb + (size_t)r * S_ + key0 + cl * 8, (char*)Vd + (i * 256 + wave * 64) * 16);
  }
}

__global__ __launch_bounds__(256) void attn_kernel(
    const u16* __restrict__ Q1, const u16* __restrict__ Q2,
    const u16* __restrict__ K1g, const u16* __restrict__ K2g,
    const u16* __restrict__ Vt, const float* __restrict__ scal,
    const float* __restrict__ subw, u16* __restrict__ attnb) {
  __shared__ u16 K1s[2][64 * 64];
  __shared__ u16 K2s[2][64 * 64];
  __shared__ u16 Vts[2][128 * 64];
  __shared__ u16 Ps1[4][16 * 64];
  __shared__ u16 Ps2[4][16 * 64];
  const int qb = blockIdx.x, h = blockIdx.y, b = blockIdx.z;
  const int tid = threadIdx.x;
  const int wave = tid >> 6, lane = tid & 63;
  const int lr = lane & 15, lkq = (lane >> 4) * 8;
  const int crow = (lane >> 4) * 4;
  const int kv = h >> 1;
  const int keybase = (h & 1) * 1024;   // buggy-repeat dedup: head h attends keys [keybase, keybase+1024)

  const int srow = qb * 64 + wave * 16 + lr;
  const u16* q1p = Q1 + (((size_t)b * NH + h) * S_ + srow) * HD + lkq;
  const u16* q2p = Q2 + (((size_t)b * NH + h) * S_ + srow) * HD + lkq;
  bf16x8v q1f[2], q2f[2];
  q1f[0] = *(const bf16x8v*)(q1p);       q1f[1] = *(const bf16x8v*)(q1p + 32);
  q2f[0] = *(const bf16x8v*)(q2p);       q2f[1] = *(const bf16x8v*)(q2p + 32);

  f32x4 O1[8] = {}, O2[8] = {};
  float m1[4], l1[4], m2[4], l2[4];
#pragma unroll
  for (int j = 0; j < 4; ++j) { m1[j] = -1e30f; l1[j] = 0.f; m2[j] = -1e30f; l2[j] = 0.f; }

  const u16* k1b = K1g + ((size_t)b * NKV + kv) * S_ * HD;
  const u16* k2b = K2g + ((size_t)b * NKV + kv) * S_ * HD;
  const u16* vb  = Vt  + ((size_t)b * NKV + kv) * 128 * S_;

  // 2-phase pipeline: prologue stage(0); per-iter: barrier -> stage(t+1 into alt) -> compute(t).
  stage_tile(k1b, k2b, vb, keybase, K1s[0], K2s[0], Vts[0], tid, wave);
  for (int ck = 0; ck < 16; ++ck) {
    const int cur = ck & 1;
    __syncthreads();   // drains stage(ck) vmcnt + fences prev-iter reads of alt buffer
    if (ck < 15)
      stage_tile(k1b, k2b, vb, keybase + (ck + 1) * 64,
                 K1s[cur ^ 1], K2s[cur ^ 1], Vts[cur ^ 1], tid, wave);
    attn_step2(K1s[cur], K2s[cur], Vts[cur], Ps1[wave], Ps2[wave],
               q1f, q2f, m1, l1, O1, m2, l2, O2, lane);
  }

  const float lam = scal[0], ofac = scal[1];
  float ssq[4] = {0.f, 0.f, 0.f, 0.f};
#pragma unroll
  for (int f = 0; f < 8; ++f)
#pragma unroll
    for (int j = 0; j < 4; ++j) {
      float cv = O1[f][j] / l1[j] - lam * (O2[f][j] / l2[j]);
      O1[f][j] = cv;
      ssq[j] += cv * cv;
    }
#pragma unroll
  for (int off = 1; off < 16; off <<= 1)
#pragma unroll
    for (int j = 0; j < 4; ++j) ssq[j] += __shfl_xor(ssq[j], off);
  float rs[4];
#pragma unroll
  for (int j = 0; j < 4; ++j) rs[j] = rsqrtf(ssq[j] * (1.f / 128.f) + EPS_) * ofac;
  const size_t rowb = (size_t)b * S_ + qb * 64 + wave * 16 + crow;
#pragma unroll
  for (int f = 0; f < 8; ++f) {
    float sw = subw[f * 16 + lr];
#pragma unroll
    for (int j = 0; j < 4; ++j)
      attnb[(rowb + j) * DIM + h * 128 + f * 16 + lr] = bfbits(O1[f][j] * rs[j] * sw);
  }
}

// ---------------- host ----------------
extern "C" void kernel_launch(void* const* d_in, const int* in_sizes, int n_in,
                              void* d_out, int out_size, void* d_ws, size_t ws_size,
                              hipStream_t stream) {
  const float* x   = (const float*)d_in[0];
  const float* wq  = (const float*)d_in[1];
  const float* wk  = (const float*)d_in[2];
  const float* wv  = (const float*)d_in[3];
  const float* wo  = (const float*)d_in[4];
  const float* lq1 = (const float*)d_in[5];
  const float* lk1 = (const float*)d_in[6];
  const float* lq2 = (const float*)d_in[7];
  const float* lk2 = (const float*)d_in[8];
  const float* li  = (const float*)d_in[9];
  const float* subw= (const float*)d_in[10];
  const float* fc  = (const float*)d_in[11];
  const float* fs  = (const float*)d_in[12];
  float* out = (float*)d_out;

  char* ws = (char*)d_ws;
  size_t off = 0;
  auto alloc = [&](size_t bytes) { char* p = ws + off; off += (bytes + 255) & ~(size_t)255; return p; };
  u16*   xb    = (u16*)alloc((size_t)ROWS * DIM * 2);
  u16*   wqkvT = (u16*)alloc((size_t)NQKV * DIM * 2);
  u16*   woT   = (u16*)alloc((size_t)DIM * DIM * 2);
  float* qkv   = (float*)alloc((size_t)ROWS * NQKV * 4);
  u16*   Q1    = (u16*)alloc((size_t)B_ * NH * S_ * HD * 2);
  u16*   Q2    = (u16*)alloc((size_t)B_ * NH * S_ * HD * 2);
  u16*   K1    = (u16*)alloc((size_t)B_ * NKV * S_ * HD * 2);
  u16*   K2    = (u16*)alloc((size_t)B_ * NKV * S_ * HD * 2);
  u16*   Vt    = (u16*)alloc((size_t)B_ * NKV * 128 * S_ * 2);
  u16*   attnb = (u16*)alloc((size_t)ROWS * DIM * 2);
  float* scal  = (float*)alloc(256);

  cast_f32_bf16<<<ROWS * DIM / 4 / 256, 256, 0, stream>>>(x, xb, ROWS * DIM / 4);
  transpose_cast<<<dim3(64, 64), dim3(32, 8), 0, stream>>>(wq, wqkvT, DIM, DIM);
  transpose_cast<<<dim3(32, 64), dim3(32, 8), 0, stream>>>(wk, wqkvT + (size_t)2048 * DIM, DIM, 1024);
  transpose_cast<<<dim3(32, 64), dim3(32, 8), 0, stream>>>(wv, wqkvT + (size_t)3072 * DIM, DIM, 1024);
  transpose_cast<<<dim3(64, 64), dim3(32, 8), 0, stream>>>(wo, woT, DIM, DIM);

  gemm8p<4><<<dim3(NQKV / 256, ROWS / 256), 512, 0, stream>>>(xb, wqkvT, qkv, ROWS, NQKV, DIM);

  rope_kernel<<<ROWS * 32 * 32 / 256, 256, 0, stream>>>(qkv, fc, fs, Q1, Q2, 5, 0);
  rope_kernel<<<ROWS * 16 * 32 / 256, 256, 0, stream>>>(qkv, fc, fs, K1, K2, 4, 2048);
  v_transpose<<<dim3(64, 4, 16), dim3(32, 8), 0, stream>>>(qkv, Vt);
  lambda_kernel<<<1, 64, 0, stream>>>(lq1, lk1, lq2, lk2, li, scal);

  attn_kernel<<<dim3(32, NH, B_), 256, 0, stream>>>(Q1, Q2, K1, K2, Vt, scal, subw, attnb);

  gemm8p<2><<<dim3(DIM / 128, ROWS / 256), 512, 0, stream>>>(attnb, woT, out, ROWS, DIM, DIM);
}